// Round 4
// baseline (557.302 us; speedup 1.0000x reference)
//
#include <hip/hip_runtime.h>

#define N 8192
#define TILE 128
#define T (N / TILE)     // 64 tiles
#define HALF (T / 2)     // 32
#define SOFT2 1.0e-4f    // 0.01^2

// Newton-3rd-law tiled kernel, v2. Block = 128 threads (2 waves) handles one
// unordered 128x128 tile pair, wrapped-diagonal coverage:
//   TI = blockIdx.x in [0,64), q = blockIdx.y in [0,32], TJ = (TI+q) & 63
//   q==32 -> antipodal pair, only TI<32 proceeds.
// Reactions accumulate via fire-and-forget LDS float atomics (ds_add_f32):
// no read-modify-write dependency chain (round-3's stall), race-safe across
// the block's two waves. Three separate float arrays -> stride-4B ds_add
// (2-way bank alias = free), vs float4's stride-16B 8-way conflict.
__global__ __launch_bounds__(TILE) void nbody_sym(
    const float* __restrict__ pos, const float* __restrict__ mass,
    float* __restrict__ out) {
  const int TI = blockIdx.x;
  const int q = blockIdx.y;
  const int TJ = (TI + q) & (T - 1);
  if (q == HALF && TI >= HALF) return;  // antipodal dedup

  __shared__ float4 jb[TILE];                        // j bodies: x,y,z,mass
  __shared__ float jax[TILE], jay[TILE], jaz[TILE];  // reaction accumulators

  const int t = threadIdx.x;
  const int i = TI * TILE + t;
  const int j = TJ * TILE + t;

  jb[t] = make_float4(pos[j * 3 + 0], pos[j * 3 + 1], pos[j * 3 + 2], mass[j]);
  jax[t] = 0.f;
  jay[t] = 0.f;
  jaz[t] = 0.f;

  const float xi = pos[i * 3 + 0];
  const float yi = pos[i * 3 + 1];
  const float zi = pos[i * 3 + 2];
  const float mi = mass[i];

  float ax = 0.f, ay = 0.f, az = 0.f;
  __syncthreads();

  if (q == 0) {
    // Diagonal tile: one-directional; j==i contributes exactly 0
    // (diff=0 -> w*0), matching the reference. Only 64/2080 blocks.
#pragma unroll 8
    for (int k = 0; k < TILE; ++k) {
      const int jj = (t + k) & (TILE - 1);
      float4 o = jb[jj];
      float dx = o.x - xi;
      float dy = o.y - yi;
      float dz = o.z - zi;
      float r2 = fmaf(dx, dx, fmaf(dy, dy, fmaf(dz, dz, SOFT2)));
      float inv = __builtin_amdgcn_rsqf(r2);
      float w = o.w * (inv * inv * inv);
      ax = fmaf(w, dx, ax);
      ay = fmaf(w, dy, ay);
      az = fmaf(w, dz, az);
    }
    atomicAdd(&out[i * 3 + 0], ax);
    atomicAdd(&out[i * 3 + 1], ay);
    atomicAdd(&out[i * 3 + 2], az);
  } else {
    // Off-diagonal: both force directions per pair, one rsq.
#pragma unroll 8
    for (int k = 0; k < TILE; ++k) {
      const int jj = (t + k) & (TILE - 1);  // skew: consecutive jj per wave
      float4 o = jb[jj];
      float dx = o.x - xi;  // d = r_j - r_i
      float dy = o.y - yi;
      float dz = o.z - zi;
      float r2 = fmaf(dx, dx, fmaf(dy, dy, fmaf(dz, dz, SOFT2)));
      float inv = __builtin_amdgcn_rsqf(r2);
      float inv3 = inv * inv * inv;
      float wj = o.w * inv3;  // m_j r^-3 -> force on i
      float wi = mi * inv3;   // m_i r^-3 -> reaction on j
      ax = fmaf(wj, dx, ax);
      ay = fmaf(wj, dy, ay);
      az = fmaf(wj, dz, az);
      atomicAdd(&jax[jj], -wi * dx);  // ds_add_f32, no return, no RMW chain
      atomicAdd(&jay[jj], -wi * dy);
      atomicAdd(&jaz[jj], -wi * dz);
    }
    atomicAdd(&out[i * 3 + 0], ax);
    atomicAdd(&out[i * 3 + 1], ay);
    atomicAdd(&out[i * 3 + 2], az);
    __syncthreads();  // drain LDS atomics from both waves
    atomicAdd(&out[j * 3 + 0], jax[t]);
    atomicAdd(&out[j * 3 + 1], jay[t]);
    atomicAdd(&out[j * 3 + 2], jaz[t]);
  }
}

extern "C" void kernel_launch(void* const* d_in, const int* in_sizes, int n_in,
                              void* d_out, int out_size, void* d_ws,
                              size_t ws_size, hipStream_t stream) {
  const float* pos = (const float*)d_in[0];
  const float* mass = (const float*)d_in[1];
  float* out = (float*)d_out;

  // Atomic accumulation needs zeros (d_out is poisoned to 0xAA pre-launch).
  hipMemsetAsync(d_out, 0, (size_t)out_size * sizeof(float), stream);

  nbody_sym<<<dim3(T, HALF + 1), TILE, 0, stream>>>(pos, mass, out);
}

// Round 5
// 82.695 us; speedup vs baseline: 6.7393x; 6.7393x over previous
//
#include <hip/hip_runtime.h>

#define N 8192
#define BLOCK 256
#define IPT 2                    // i-bodies per thread (register blocking)
#define ITILE (BLOCK * IPT)      // 512 i-bodies per block
#define NITILES (N / ITILE)      // 16
#define SLABS 32
#define JCHUNK (N / SLABS)       // 256 j-bodies per block
#define SOFT2 1.0e-4f            // 0.01^2

// Lessons from rounds 2-4: the ONLY cheap LDS access pattern here is the
// wave-uniform broadcast (same address, all lanes). Per-lane scattered LDS
// (skewed reads = bank conflicts; RMW = lgkm dependency chain; LDS atomics =
// full serialization, 505 us) costs more than Newton-symmetry saves.
// So: one-directional forces, broadcast-only LDS reads, and IPT=2 register
// blocking so each ds_read_b128 broadcast feeds 2 pair computations ->
// LDS pipe (8 waves/CU x 8cy / 2 pairs) sits well under the VALU demand.
// Grid = 16 i-tiles x 32 j-slabs = 512 blocks = 2/CU = 8 waves/CU.
__global__ __launch_bounds__(BLOCK) void nbody_kernel(
    const float* __restrict__ pos, const float* __restrict__ mass,
    float* __restrict__ out) {
  __shared__ float4 jb[JCHUNK];

  const int t = threadIdx.x;
  const int j = blockIdx.y * JCHUNK + t;  // stage this block's j-slab
  jb[t] = make_float4(pos[j * 3 + 0], pos[j * 3 + 1], pos[j * 3 + 2], mass[j]);

  const int i0 = blockIdx.x * ITILE + t;  // two i-bodies, stride-256 so the
  const int i1 = i0 + BLOCK;              // loads and atomics stay coalesced
  const float xi0 = pos[i0 * 3 + 0], yi0 = pos[i0 * 3 + 1],
              zi0 = pos[i0 * 3 + 2];
  const float xi1 = pos[i1 * 3 + 0], yi1 = pos[i1 * 3 + 1],
              zi1 = pos[i1 * 3 + 2];

  float ax0 = 0.f, ay0 = 0.f, az0 = 0.f;
  float ax1 = 0.f, ay1 = 0.f, az1 = 0.f;

  __syncthreads();

#pragma unroll 4
  for (int k = 0; k < JCHUNK; ++k) {
    float4 o = jb[k];  // wave-uniform address -> LDS broadcast, conflict-free
    {
      float dx = o.x - xi0, dy = o.y - yi0, dz = o.z - zi0;
      float r2 = fmaf(dx, dx, fmaf(dy, dy, fmaf(dz, dz, SOFT2)));
      float inv = __builtin_amdgcn_rsqf(r2);
      float w = o.w * (inv * inv * inv);
      ax0 = fmaf(w, dx, ax0);
      ay0 = fmaf(w, dy, ay0);
      az0 = fmaf(w, dz, az0);
    }
    {
      float dx = o.x - xi1, dy = o.y - yi1, dz = o.z - zi1;
      float r2 = fmaf(dx, dx, fmaf(dy, dy, fmaf(dz, dz, SOFT2)));
      float inv = __builtin_amdgcn_rsqf(r2);
      float w = o.w * (inv * inv * inv);
      ax1 = fmaf(w, dx, ax1);
      ay1 = fmaf(w, dy, ay1);
      az1 = fmaf(w, dz, az1);
    }
  }

  // 32 slab-partials per body; L2-side float atomics, ~786K total.
  atomicAdd(&out[i0 * 3 + 0], ax0);
  atomicAdd(&out[i0 * 3 + 1], ay0);
  atomicAdd(&out[i0 * 3 + 2], az0);
  atomicAdd(&out[i1 * 3 + 0], ax1);
  atomicAdd(&out[i1 * 3 + 1], ay1);
  atomicAdd(&out[i1 * 3 + 2], az1);
}

extern "C" void kernel_launch(void* const* d_in, const int* in_sizes, int n_in,
                              void* d_out, int out_size, void* d_ws,
                              size_t ws_size, hipStream_t stream) {
  const float* pos = (const float*)d_in[0];
  const float* mass = (const float*)d_in[1];
  float* out = (float*)d_out;

  // Atomic accumulation needs zeros (d_out is poisoned to 0xAA pre-launch).
  hipMemsetAsync(d_out, 0, (size_t)out_size * sizeof(float), stream);

  nbody_kernel<<<dim3(NITILES, SLABS), BLOCK, 0, stream>>>(pos, mass, out);
}

// Round 6
// 81.116 us; speedup vs baseline: 6.8704x; 1.0195x over previous
//
#include <hip/hip_runtime.h>

#define N 8192
#define BLOCK 256
#define IPT 2                    // i-bodies per thread (register blocking)
#define ITILE (BLOCK * IPT)      // 512 i-bodies per block
#define NITILES (N / ITILE)      // 16
#define SLABS 64
#define JCHUNK (N / SLABS)       // 128 j-bodies per block
#define SOFT2 1.0e-4f            // 0.01^2

// Broadcast-only LDS structure (rounds 2-4 showed every per-lane LDS pattern
// — skewed reads, RMW, LDS atomics — loses more than Newton symmetry saves).
// Round 5 at SLABS=32 ran ~28 us: only 2 waves/SIMD, VALU idled on the
// ~50cy per-pair dependency chain. SLABS=64 -> 1024 blocks = 4 blocks/CU =
// 16 waves/CU = 4 waves/SIMD for latency hiding; IPT=2 keeps 2 independent
// chains per thread and halves broadcast reads per pair.
__global__ __launch_bounds__(BLOCK) void nbody_kernel(
    const float* __restrict__ pos, const float* __restrict__ mass,
    float* __restrict__ out) {
  __shared__ float4 jb[JCHUNK];

  const int t = threadIdx.x;
  if (t < JCHUNK) {
    const int j = blockIdx.y * JCHUNK + t;
    jb[t] =
        make_float4(pos[j * 3 + 0], pos[j * 3 + 1], pos[j * 3 + 2], mass[j]);
  }

  const int i0 = blockIdx.x * ITILE + t;  // two i-bodies, stride-256 so the
  const int i1 = i0 + BLOCK;              // loads and atomics stay coalesced
  const float xi0 = pos[i0 * 3 + 0], yi0 = pos[i0 * 3 + 1],
              zi0 = pos[i0 * 3 + 2];
  const float xi1 = pos[i1 * 3 + 0], yi1 = pos[i1 * 3 + 1],
              zi1 = pos[i1 * 3 + 2];

  float ax0 = 0.f, ay0 = 0.f, az0 = 0.f;
  float ax1 = 0.f, ay1 = 0.f, az1 = 0.f;

  __syncthreads();

#pragma unroll 8
  for (int k = 0; k < JCHUNK; ++k) {
    float4 o = jb[k];  // wave-uniform address -> LDS broadcast, conflict-free
    {
      float dx = o.x - xi0, dy = o.y - yi0, dz = o.z - zi0;
      float r2 = fmaf(dx, dx, fmaf(dy, dy, fmaf(dz, dz, SOFT2)));
      float inv = __builtin_amdgcn_rsqf(r2);
      float w = o.w * (inv * inv * inv);
      ax0 = fmaf(w, dx, ax0);
      ay0 = fmaf(w, dy, ay0);
      az0 = fmaf(w, dz, az0);
    }
    {
      float dx = o.x - xi1, dy = o.y - yi1, dz = o.z - zi1;
      float r2 = fmaf(dx, dx, fmaf(dy, dy, fmaf(dz, dz, SOFT2)));
      float inv = __builtin_amdgcn_rsqf(r2);
      float w = o.w * (inv * inv * inv);
      ax1 = fmaf(w, dx, ax1);
      ay1 = fmaf(w, dy, ay1);
      az1 = fmaf(w, dz, az1);
    }
  }

  // 64 slab-partials per body; L2-side float atomics, ~1.57M total.
  atomicAdd(&out[i0 * 3 + 0], ax0);
  atomicAdd(&out[i0 * 3 + 1], ay0);
  atomicAdd(&out[i0 * 3 + 2], az0);
  atomicAdd(&out[i1 * 3 + 0], ax1);
  atomicAdd(&out[i1 * 3 + 1], ay1);
  atomicAdd(&out[i1 * 3 + 2], az1);
}

extern "C" void kernel_launch(void* const* d_in, const int* in_sizes, int n_in,
                              void* d_out, int out_size, void* d_ws,
                              size_t ws_size, hipStream_t stream) {
  const float* pos = (const float*)d_in[0];
  const float* mass = (const float*)d_in[1];
  float* out = (float*)d_out;

  // Atomic accumulation needs zeros (d_out is poisoned to 0xAA pre-launch).
  hipMemsetAsync(d_out, 0, (size_t)out_size * sizeof(float), stream);

  nbody_kernel<<<dim3(NITILES, SLABS), BLOCK, 0, stream>>>(pos, mass, out);
}